// Round 11
// baseline (153.004 us; speedup 1.0000x reference)
//
#include <hip/hip_runtime.h>
#include <hip/hip_bf16.h>
#include <stdint.h>

typedef __attribute__((ext_vector_type(8))) short short8;
typedef __attribute__((ext_vector_type(4))) float f32x4;

#define DDIM 128

__device__ __forceinline__ unsigned short f2bf(float f) {
  union { float f; unsigned u; } v; v.f = f;
  unsigned u = v.u + 0x7FFFu + ((v.u >> 16) & 1u);  // RNE
  return (unsigned short)(u >> 16);
}
__device__ __forceinline__ float bf2f(unsigned short b) {
  union { unsigned u; float f; } v; v.u = ((unsigned)b) << 16;
  return v.f;
}

// ---- weights fp32 -> bf16 staging: wb = [W1 rows; W2 rows] = [256][128]
__global__ void convW(const float* __restrict__ W1, const float* __restrict__ W2,
                      unsigned short* __restrict__ wb) {
  int i = blockIdx.x * blockDim.x + threadIdx.x;
  if (i < 16384)      wb[i] = f2bf(W1[i]);
  else if (i < 32768) wb[i] = f2bf(W2[i - 16384]);
}

// ---- proj v4.1: persistent, 8 blocks/CU (grid 2048) for cross-block
//      stage/MFMA overlap. W fragments once per block from bf16 wb.
//      A = bf16(y1+b1+y2+b2), Q = bf16(y2). P reconstructed in pullfin.
__global__ __launch_bounds__(256) void proj(
    const float* __restrict__ xu, int NUr, int gU,
    const float* __restrict__ xi, int NIr, int nTiles,
    const unsigned short* __restrict__ wb,
    const float* __restrict__ b1, const float* __restrict__ b2,
    unsigned short* __restrict__ Au, unsigned short* __restrict__ Qu,
    unsigned short* __restrict__ Ai, unsigned short* __restrict__ Qi) {
  __shared__ unsigned short xs[64 * DDIM];   // 16 KB, XOR-swizzled
  const int tid   = threadIdx.x;
  const int lane  = tid & 63;
  const int wv    = tid >> 6;
  const int col16 = lane & 15;
  const int kgrp  = lane >> 4;

  short8 wf[2][2][4];
#pragma unroll
  for (int m = 0; m < 2; ++m)
#pragma unroll
    for (int ct = 0; ct < 2; ++ct) {
      const int c = m * 128 + wv * 32 + ct * 16 + col16;
#pragma unroll
      for (int ks = 0; ks < 4; ++ks)
        wf[m][ct][ks] = *(const short8*)(wb + (size_t)c * DDIM + ks * 32 + kgrp * 8);
    }
  float b1c[2], b2c[2];
#pragma unroll
  for (int ct = 0; ct < 2; ++ct) {
    const int c = wv * 32 + ct * 16 + col16;
    b1c[ct] = b1[c];
    b2c[ct] = b2[c];
  }

  for (int t = blockIdx.x; t < nTiles; t += gridDim.x) {
    const bool isU = (t < gU);
    const float* __restrict__ x = isU ? xu : xi;
    const int nrows = isU ? NUr : NIr;
    const int tt    = isU ? t : (t - gU);
    unsigned short* __restrict__ Aout = isU ? Au : Ai;
    unsigned short* __restrict__ Qout = isU ? Qu : Qi;
    const int r0 = tt * 64;

    // ---- stage 64x128 f32 -> bf16 LDS, coalesced
#pragma unroll
    for (int i = 0; i < 8; ++i) {
      const int flat = i * 1024 + tid * 4;
      const int rr = flat >> 7, cc = flat & 127;
      float4 v;
      if (r0 + rr < nrows) v = *(const float4*)(x + (size_t)(r0 + rr) * DDIM + cc);
      else                 v = make_float4(0.f, 0.f, 0.f, 0.f);
      uint2 pk;
      pk.x = ((unsigned)f2bf(v.y) << 16) | f2bf(v.x);
      pk.y = ((unsigned)f2bf(v.w) << 16) | f2bf(v.z);
      const int byte = (rr * 256 + cc * 2) ^ ((rr & 7) << 4);
      *(uint2*)((char*)xs + byte) = pk;
    }
    __syncthreads();

    // ---- MFMA
    f32x4 acc[4][2][2];
#pragma unroll
    for (int rt = 0; rt < 4; ++rt)
#pragma unroll
      for (int m = 0; m < 2; ++m)
#pragma unroll
        for (int ct = 0; ct < 2; ++ct)
          acc[rt][m][ct] = (f32x4){0.f, 0.f, 0.f, 0.f};

#pragma unroll
    for (int ks = 0; ks < 4; ++ks) {
#pragma unroll
      for (int rt = 0; rt < 4; ++rt) {
        const int rr = rt * 16 + col16;
        const int byte = (rr * 256 + (ks * 64 + kgrp * 16)) ^ ((rr & 7) << 4);
        short8 a = *(const short8*)((char*)xs + byte);
#pragma unroll
        for (int m = 0; m < 2; ++m)
#pragma unroll
          for (int ct = 0; ct < 2; ++ct)
            acc[rt][m][ct] = __builtin_amdgcn_mfma_f32_16x16x32_bf16(a, wf[m][ct][ks], acc[rt][m][ct], 0, 0, 0);
      }
    }

    // ---- epilogue
#pragma unroll
    for (int rt = 0; rt < 4; ++rt)
#pragma unroll
      for (int ct = 0; ct < 2; ++ct) {
        const int c = wv * 32 + ct * 16 + col16;
#pragma unroll
        for (int i = 0; i < 4; ++i) {
          const int r = r0 + rt * 16 + kgrp * 4 + i;
          if (r < nrows) {
            const float y1 = acc[rt][0][ct][i] + b1c[ct];
            const float y2 = acc[rt][1][ct][i];
            Aout[(size_t)r * DDIM + c] = f2bf(y1 + y2 + b2c[ct]);
            Qout[(size_t)r * DDIM + c] = f2bf(y2);
          }
        }
      }
    __syncthreads();  // protect xs before next tile's stage
  }
}

// ---- hist: rank[i] = per-dst arrival index; ONE atomic per edge.
__global__ void hist(const int* __restrict__ dst_ui, int nE_ui,
                     const int* __restrict__ dst_iu, int nE_iu,
                     int NU, int* __restrict__ deg, int* __restrict__ rank) {
  int i = blockIdx.x * blockDim.x + threadIdx.x;
  const int stride = gridDim.x * blockDim.x;
  const int nTot = nE_ui + nE_iu;
  for (; i < nTot; i += stride) {
    const int d = (i < nE_ui) ? (NU + dst_ui[i]) : dst_iu[i - nE_ui];
    rank[i] = atomicAdd(&deg[d], 1);
  }
}

__global__ __launch_bounds__(1024) void scan1(const int* __restrict__ deg, int n,
                                              int* __restrict__ exsc, int* __restrict__ bsum) {
  __shared__ int wsum[16];
  const int tid = threadIdx.x;
  const int g = blockIdx.x * 1024 + tid;
  const int lane = tid & 63, wv = tid >> 6;
  int v = (g < n) ? deg[g] : 0;
  int x = v;
#pragma unroll
  for (int off = 1; off < 64; off <<= 1) {
    int y = __shfl_up(x, off);
    if (lane >= off) x += y;
  }
  if (lane == 63) wsum[wv] = x;
  __syncthreads();
  if (wv == 0 && lane < 16) {
    int s = wsum[lane];
#pragma unroll
    for (int off = 1; off < 16; off <<= 1) {
      int y = __shfl_up(s, off);
      if (lane >= off) s += y;
    }
    wsum[lane] = s;
  }
  __syncthreads();
  int woff = (wv == 0) ? 0 : wsum[wv - 1];
  int inc = x + woff;
  if (g < n) exsc[g] = inc - v;
  if (tid == 1023) bsum[blockIdx.x] = inc;
}

__global__ __launch_bounds__(256) void scan2(int* __restrict__ bsum, int nb) {
  __shared__ int tmp[256];
  const int tid = threadIdx.x;
  int v = (tid < nb) ? bsum[tid] : 0;
  int x = v;
  tmp[tid] = v;
  __syncthreads();
#pragma unroll
  for (int off = 1; off < 256; off <<= 1) {
    int y = (tid >= off) ? tmp[tid - off] : 0;
    __syncthreads();
    x += y;
    tmp[tid] = x;
    __syncthreads();
  }
  if (tid < nb) bsum[tid] = x - v;
}

__global__ void scan3(const int* __restrict__ exsc, const int* __restrict__ bsum,
                      int n, int nETot, int* __restrict__ rowptr) {
  int g = blockIdx.x * blockDim.x + threadIdx.x;
  if (g < n) rowptr[g] = exsc[g] + bsum[g >> 10];
  if (g == n) rowptr[n] = nETot;
}

// ---- fillcsr: ATOMIC-FREE — pos = rowptr[dst] + rank[i]
__global__ void fillcsr(const int* __restrict__ src_ui, const int* __restrict__ dst_ui,
                        const float* __restrict__ nrm_ui, int nE_ui,
                        const int* __restrict__ src_iu, const int* __restrict__ dst_iu,
                        const float* __restrict__ nrm_iu, int nE_iu,
                        int NU, const int* __restrict__ rowptr,
                        const int* __restrict__ rank, int2* __restrict__ pay) {
  int i = blockIdx.x * blockDim.x + threadIdx.x;
  int stride = gridDim.x * blockDim.x;
  int nTot = nE_ui + nE_iu;
  for (; i < nTot; i += stride) {
    int d, s; float nm;
    if (i < nE_ui) { d = NU + dst_ui[i]; s = src_ui[i]; nm = nrm_ui[i]; }
    else { int k = i - nE_ui; d = dst_iu[k]; s = src_iu[k]; nm = nrm_iu[k]; }
    const int pos = rowptr[d] + rank[i];
    int2 p; p.x = s; p.y = __float_as_int(nm);
    pay[pos] = p;
  }
}

// ---- pullfin v3: S computed inline from payload norms.
// h[r] = A_self[r] + (S-1)*Q[r] - b2 + sum_e norm_e * A_gather[src_e]; lrelu+L2norm.
__global__ __launch_bounds__(256) void pullfin(
    const int* __restrict__ rowptr, const int2* __restrict__ pay,
    const unsigned short* __restrict__ Ac,
    const unsigned short* __restrict__ Au, const unsigned short* __restrict__ Ai,
    const unsigned short* __restrict__ Qc,
    const float* __restrict__ b2,
    float* __restrict__ out, int NU, int ntot) {
  const int lane = threadIdx.x & 63;
  const int h    = lane & 31;
  const int half = lane >> 5;
  float b2v[4];
#pragma unroll
  for (int j = 0; j < 4; ++j) b2v[j] = b2[h * 4 + j];

  int r = (((blockIdx.x * blockDim.x + threadIdx.x) >> 6) << 1) + half;
  const int rstride = ((gridDim.x * blockDim.x) >> 6) << 1;
  for (; r < ntot; r += rstride) {
    const unsigned short* Ag = (r < NU) ? Ai : Au;
    const int beg = rowptr[r], end = rowptr[r + 1];
    float a0 = 0.f, a1 = 0.f, a2 = 0.f, a3 = 0.f, sn = 0.f;
    int e = beg;
    for (; e + 3 < end; e += 4) {
      int2 p0 = pay[e], p1 = pay[e + 1], p2 = pay[e + 2], p3 = pay[e + 3];
      uint2 g0 = *(const uint2*)(Ag + (size_t)p0.x * DDIM + h * 4);
      uint2 g1 = *(const uint2*)(Ag + (size_t)p1.x * DDIM + h * 4);
      uint2 g2 = *(const uint2*)(Ag + (size_t)p2.x * DDIM + h * 4);
      uint2 g3 = *(const uint2*)(Ag + (size_t)p3.x * DDIM + h * 4);
      float n0 = __int_as_float(p0.y), n1 = __int_as_float(p1.y);
      float n2 = __int_as_float(p2.y), n3 = __int_as_float(p3.y);
      sn += (n0 + n1) + (n2 + n3);
      a0 += n0 * bf2f((unsigned short)(g0.x & 0xffffu));
      a1 += n0 * bf2f((unsigned short)(g0.x >> 16));
      a2 += n0 * bf2f((unsigned short)(g0.y & 0xffffu));
      a3 += n0 * bf2f((unsigned short)(g0.y >> 16));
      a0 += n1 * bf2f((unsigned short)(g1.x & 0xffffu));
      a1 += n1 * bf2f((unsigned short)(g1.x >> 16));
      a2 += n1 * bf2f((unsigned short)(g1.y & 0xffffu));
      a3 += n1 * bf2f((unsigned short)(g1.y >> 16));
      a0 += n2 * bf2f((unsigned short)(g2.x & 0xffffu));
      a1 += n2 * bf2f((unsigned short)(g2.x >> 16));
      a2 += n2 * bf2f((unsigned short)(g2.y & 0xffffu));
      a3 += n2 * bf2f((unsigned short)(g2.y >> 16));
      a0 += n3 * bf2f((unsigned short)(g3.x & 0xffffu));
      a1 += n3 * bf2f((unsigned short)(g3.x >> 16));
      a2 += n3 * bf2f((unsigned short)(g3.y & 0xffffu));
      a3 += n3 * bf2f((unsigned short)(g3.y >> 16));
    }
    for (; e < end; ++e) {
      int2 p0 = pay[e];
      uint2 g0 = *(const uint2*)(Ag + (size_t)p0.x * DDIM + h * 4);
      float n0 = __int_as_float(p0.y);
      sn += n0;
      a0 += n0 * bf2f((unsigned short)(g0.x & 0xffffu));
      a1 += n0 * bf2f((unsigned short)(g0.x >> 16));
      a2 += n0 * bf2f((unsigned short)(g0.y & 0xffffu));
      a3 += n0 * bf2f((unsigned short)(g0.y >> 16));
    }

    uint2 av = *(const uint2*)(Ac + (size_t)r * DDIM + h * 4);
    uint2 qv = *(const uint2*)(Qc + (size_t)r * DDIM + h * 4);
    const float s1 = sn - 1.0f;
    float v0 = bf2f((unsigned short)(av.x & 0xffffu)) + s1 * bf2f((unsigned short)(qv.x & 0xffffu)) - b2v[0] + a0;
    float v1 = bf2f((unsigned short)(av.x >> 16))     + s1 * bf2f((unsigned short)(qv.x >> 16))     - b2v[1] + a1;
    float v2 = bf2f((unsigned short)(av.y & 0xffffu)) + s1 * bf2f((unsigned short)(qv.y & 0xffffu)) - b2v[2] + a2;
    float v3 = bf2f((unsigned short)(av.y >> 16))     + s1 * bf2f((unsigned short)(qv.y >> 16))     - b2v[3] + a3;

    v0 = v0 > 0.f ? v0 : 0.2f * v0;
    v1 = v1 > 0.f ? v1 : 0.2f * v1;
    v2 = v2 > 0.f ? v2 : 0.2f * v2;
    v3 = v3 > 0.f ? v3 : 0.2f * v3;
    float sq = v0 * v0 + v1 * v1 + v2 * v2 + v3 * v3;
#pragma unroll
    for (int off = 16; off; off >>= 1) sq += __shfl_xor(sq, off);
    float sc = 1.0f / fmaxf(sqrtf(sq), 1e-12f);
    f32x4 res;
    res.x = v0 * sc; res.y = v1 * sc; res.z = v2 * sc; res.w = v3 * sc;
    __builtin_nontemporal_store(res, (f32x4*)(out + (size_t)r * DDIM + h * 4));
  }
}

extern "C" void kernel_launch(void* const* d_in, const int* in_sizes, int n_in,
                              void* d_out, int out_size, void* d_ws, size_t ws_size,
                              hipStream_t stream) {
  const float* x_user  = (const float*)d_in[0];
  const float* x_item  = (const float*)d_in[1];
  const float* W1      = (const float*)d_in[2];
  const float* b1      = (const float*)d_in[3];
  const float* W2      = (const float*)d_in[4];
  const float* b2      = (const float*)d_in[5];
  const int*   src_ui  = (const int*)d_in[6];
  const int*   dst_ui  = (const int*)d_in[7];
  const float* norm_ui = (const float*)d_in[8];
  const int*   src_iu  = (const int*)d_in[9];
  const int*   dst_iu  = (const int*)d_in[10];
  const float* norm_iu = (const float*)d_in[11];

  const int NUr   = in_sizes[0] / DDIM;   // 100000
  const int NIr   = in_sizes[1] / DDIM;   // 50000
  const int nE_ui = in_sizes[6];          // 300000
  const int nE_iu = in_sizes[9];
  const int nTot  = NUr + NIr;
  const int nETot = nE_ui + nE_iu;

  float* out = (float*)d_out;             // rows: [h_user (NUr); h_item (NIr)]

  char* ws = (char*)d_ws;
  size_t off = 0;
  auto alloc = [&](size_t bytes) { char* p = ws + off; off += (bytes + 15) & ~(size_t)15; return p; };
  unsigned short* wb  = (unsigned short*)alloc(32768 * 2);
  unsigned short* Ac  = (unsigned short*)alloc((size_t)nTot * DDIM * 2);  // [Au; Ai]
  unsigned short* Qc  = (unsigned short*)alloc((size_t)nTot * DDIM * 2);  // [Qu; Qi]
  int*   deg          = (int*)alloc((size_t)nTot * 4);
  int*   exsc         = (int*)alloc((size_t)nTot * 4);
  int*   bsum         = (int*)alloc(256 * 4);
  int*   rowptr       = (int*)alloc(((size_t)nTot + 1) * 4);
  int*   rank         = (int*)alloc((size_t)nETot * 4);
  int2*  pay          = (int2*)alloc((size_t)nETot * 8);

  unsigned short* Au = Ac;
  unsigned short* Ai = Ac + (size_t)NUr * DDIM;
  unsigned short* Qu = Qc;
  unsigned short* Qi = Qc + (size_t)NUr * DDIM;

  (void)hipMemsetAsync(deg, 0, (size_t)nTot * 4, stream);

  const int gU = (NUr + 63) / 64;         // 1563
  const int gI = (NIr + 63) / 64;         // 782
  const int nTiles = gU + gI;             // 2345

  convW<<<128, 256, 0, stream>>>(W1, W2, wb);
  proj<<<2048, 256, 0, stream>>>(x_user, NUr, gU, x_item, NIr, nTiles,
                                 wb, b1, b2, Au, Qu, Ai, Qi);
  hist<<<4096, 256, 0, stream>>>(dst_ui, nE_ui, dst_iu, nE_iu, NUr, deg, rank);

  const int nb = (nTot + 1023) / 1024;    // 147
  scan1<<<nb, 1024, 0, stream>>>(deg, nTot, exsc, bsum);
  scan2<<<1, 256, 0, stream>>>(bsum, nb);
  scan3<<<(nTot + 256) / 256, 256, 0, stream>>>(exsc, bsum, nTot, nETot, rowptr);
  fillcsr<<<2048, 256, 0, stream>>>(src_ui, dst_ui, norm_ui, nE_ui,
                                    src_iu, dst_iu, norm_iu, nE_iu, NUr, rowptr, rank, pay);
  pullfin<<<18752, 256, 0, stream>>>(rowptr, pay, Ac, Au, Ai, Qc, b2, out, NUr, nTot);
}

// Round 12
// 152.425 us; speedup vs baseline: 1.0038x; 1.0038x over previous
//
#include <hip/hip_runtime.h>
#include <hip/hip_bf16.h>
#include <stdint.h>

typedef __attribute__((ext_vector_type(8))) short short8;
typedef __attribute__((ext_vector_type(4))) float f32x4;

#define DDIM 128

__device__ __forceinline__ unsigned short f2bf(float f) {
  union { float f; unsigned u; } v; v.f = f;
  unsigned u = v.u + 0x7FFFu + ((v.u >> 16) & 1u);  // RNE
  return (unsigned short)(u >> 16);
}
__device__ __forceinline__ float bf2f(unsigned short b) {
  union { unsigned u; float f; } v; v.u = ((unsigned)b) << 16;
  return v.f;
}
// packed f32 pair -> 2x bf16 in one u32 (v_cvt_pk_bf16_f32, RNE)
__device__ __forceinline__ unsigned pack2(float lo, float hi) {
  __hip_bfloat162 h2 = __float22bfloat162_rn(make_float2(lo, hi));
  unsigned u; __builtin_memcpy(&u, &h2, 4); return u;
}

// ---- weights fp32 -> bf16 staging: wb = [W1 rows; W2 rows] = [256][128]
__global__ void convW(const float* __restrict__ W1, const float* __restrict__ W2,
                      unsigned short* __restrict__ wb) {
  int i = blockIdx.x * blockDim.x + threadIdx.x;
  if (i < 16384)      wb[i] = f2bf(W1[i]);
  else if (i < 32768) wb[i] = f2bf(W2[i - 16384]);
}

// ---- proj v5: swapped MFMA operands -> thread holds 4 consecutive output
//      cols per fragment -> ushort4 packed stores (16x8B vs 64x2B). Packed
//      cvt for all f32->bf16. Persistent, grid 1024.
__global__ __launch_bounds__(256) void proj(
    const float* __restrict__ xu, int NUr, int gU,
    const float* __restrict__ xi, int NIr, int nTiles,
    const unsigned short* __restrict__ wb,
    const float* __restrict__ b1, const float* __restrict__ b2,
    unsigned short* __restrict__ Au, unsigned short* __restrict__ Qu,
    unsigned short* __restrict__ Ai, unsigned short* __restrict__ Qi) {
  __shared__ unsigned short xs[64 * DDIM];   // 16 KB, XOR-swizzled
  const int tid   = threadIdx.x;
  const int lane  = tid & 63;
  const int wv    = tid >> 6;
  const int col16 = lane & 15;
  const int kgrp  = lane >> 4;

  // W fragments once per block (A-operand: lane holds W-row col16, k-chunk kgrp*8)
  short8 wf[2][2][4];
#pragma unroll
  for (int m = 0; m < 2; ++m)
#pragma unroll
    for (int ct = 0; ct < 2; ++ct) {
      const int c = m * 128 + wv * 32 + ct * 16 + col16;
#pragma unroll
      for (int ks = 0; ks < 4; ++ks)
        wf[m][ct][ks] = *(const short8*)(wb + (size_t)c * DDIM + ks * 32 + kgrp * 8);
    }
  // per-thread bias for the 4 consecutive cols this thread owns per ct
  float4 bc12[2], b2o[2];   // bc12 = b1+b2 (for A), b2 unused for Q
#pragma unroll
  for (int ct = 0; ct < 2; ++ct) {
    const int cb = wv * 32 + ct * 16 + kgrp * 4;
    float4 v1 = *(const float4*)(b1 + cb);
    float4 v2 = *(const float4*)(b2 + cb);
    bc12[ct] = make_float4(v1.x + v2.x, v1.y + v2.y, v1.z + v2.z, v1.w + v2.w);
    b2o[ct] = v2;
  }
  (void)b2o;

  for (int t = blockIdx.x; t < nTiles; t += gridDim.x) {
    const bool isU = (t < gU);
    const float* __restrict__ x = isU ? xu : xi;
    const int nrows = isU ? NUr : NIr;
    const int tt    = isU ? t : (t - gU);
    unsigned short* __restrict__ Aout = isU ? Au : Ai;
    unsigned short* __restrict__ Qout = isU ? Qu : Qi;
    const int r0 = tt * 64;

    // ---- stage 64x128 f32 -> bf16 LDS, coalesced, packed cvt
#pragma unroll
    for (int i = 0; i < 8; ++i) {
      const int flat = i * 1024 + tid * 4;
      const int rr = flat >> 7, cc = flat & 127;
      float4 v;
      if (r0 + rr < nrows) v = *(const float4*)(x + (size_t)(r0 + rr) * DDIM + cc);
      else                 v = make_float4(0.f, 0.f, 0.f, 0.f);
      uint2 pk;
      pk.x = pack2(v.x, v.y);
      pk.y = pack2(v.z, v.w);
      const int byte = (rr * 256 + cc * 2) ^ ((rr & 7) << 4);
      *(uint2*)((char*)xs + byte) = pk;
    }
    __syncthreads();

    // ---- MFMA (swapped: wf = A-operand, x = B-operand)
    f32x4 acc[4][2][2];
#pragma unroll
    for (int rt = 0; rt < 4; ++rt)
#pragma unroll
      for (int m = 0; m < 2; ++m)
#pragma unroll
        for (int ct = 0; ct < 2; ++ct)
          acc[rt][m][ct] = (f32x4){0.f, 0.f, 0.f, 0.f};

#pragma unroll
    for (int ks = 0; ks < 4; ++ks) {
#pragma unroll
      for (int rt = 0; rt < 4; ++rt) {
        const int rr = rt * 16 + col16;
        const int byte = (rr * 256 + (ks * 64 + kgrp * 16)) ^ ((rr & 7) << 4);
        short8 a = *(const short8*)((char*)xs + byte);
#pragma unroll
        for (int m = 0; m < 2; ++m)
#pragma unroll
          for (int ct = 0; ct < 2; ++ct)
            acc[rt][m][ct] = __builtin_amdgcn_mfma_f32_16x16x32_bf16(wf[m][ct][ks], a, acc[rt][m][ct], 0, 0, 0);
      }
    }

    // ---- epilogue: D[c][r] layout -> thread owns row r=r0+rt*16+col16,
    //      cols cb..cb+3 (cb = wv*32+ct*16+kgrp*4): packed 8B stores.
#pragma unroll
    for (int rt = 0; rt < 4; ++rt) {
      const int r = r0 + rt * 16 + col16;
      if (r < nrows) {
#pragma unroll
        for (int ct = 0; ct < 2; ++ct) {
          const int cb = wv * 32 + ct * 16 + kgrp * 4;
          const f32x4 y1 = acc[rt][0][ct];
          const f32x4 y2 = acc[rt][1][ct];
          uint2 ap, qp;
          ap.x = pack2(y1[0] + y2[0] + bc12[ct].x, y1[1] + y2[1] + bc12[ct].y);
          ap.y = pack2(y1[2] + y2[2] + bc12[ct].z, y1[3] + y2[3] + bc12[ct].w);
          qp.x = pack2(y2[0], y2[1]);
          qp.y = pack2(y2[2], y2[3]);
          *(uint2*)(Aout + (size_t)r * DDIM + cb) = ap;
          *(uint2*)(Qout + (size_t)r * DDIM + cb) = qp;
        }
      }
    }
    __syncthreads();  // protect xs before next tile's stage
  }
}

// ---- hist: rank[i] = per-dst arrival index; ONE atomic per edge.
__global__ void hist(const int* __restrict__ dst_ui, int nE_ui,
                     const int* __restrict__ dst_iu, int nE_iu,
                     int NU, int* __restrict__ deg, int* __restrict__ rank) {
  int i = blockIdx.x * blockDim.x + threadIdx.x;
  const int stride = gridDim.x * blockDim.x;
  const int nTot = nE_ui + nE_iu;
  for (; i < nTot; i += stride) {
    const int d = (i < nE_ui) ? (NU + dst_ui[i]) : dst_iu[i - nE_ui];
    rank[i] = atomicAdd(&deg[d], 1);
  }
}

__global__ __launch_bounds__(1024) void scan1(const int* __restrict__ deg, int n,
                                              int* __restrict__ exsc, int* __restrict__ bsum) {
  __shared__ int wsum[16];
  const int tid = threadIdx.x;
  const int g = blockIdx.x * 1024 + tid;
  const int lane = tid & 63, wv = tid >> 6;
  int v = (g < n) ? deg[g] : 0;
  int x = v;
#pragma unroll
  for (int off = 1; off < 64; off <<= 1) {
    int y = __shfl_up(x, off);
    if (lane >= off) x += y;
  }
  if (lane == 63) wsum[wv] = x;
  __syncthreads();
  if (wv == 0 && lane < 16) {
    int s = wsum[lane];
#pragma unroll
    for (int off = 1; off < 16; off <<= 1) {
      int y = __shfl_up(s, off);
      if (lane >= off) s += y;
    }
    wsum[lane] = s;
  }
  __syncthreads();
  int woff = (wv == 0) ? 0 : wsum[wv - 1];
  int inc = x + woff;
  if (g < n) exsc[g] = inc - v;
  if (tid == 1023) bsum[blockIdx.x] = inc;
}

__global__ __launch_bounds__(256) void scan2(int* __restrict__ bsum, int nb) {
  __shared__ int tmp[256];
  const int tid = threadIdx.x;
  int v = (tid < nb) ? bsum[tid] : 0;
  int x = v;
  tmp[tid] = v;
  __syncthreads();
#pragma unroll
  for (int off = 1; off < 256; off <<= 1) {
    int y = (tid >= off) ? tmp[tid - off] : 0;
    __syncthreads();
    x += y;
    tmp[tid] = x;
    __syncthreads();
  }
  if (tid < nb) bsum[tid] = x - v;
}

__global__ void scan3(const int* __restrict__ exsc, const int* __restrict__ bsum,
                      int n, int nETot, int* __restrict__ rowptr) {
  int g = blockIdx.x * blockDim.x + threadIdx.x;
  if (g < n) rowptr[g] = exsc[g] + bsum[g >> 10];
  if (g == n) rowptr[n] = nETot;
}

// ---- fillcsr: ATOMIC-FREE — pos = rowptr[dst] + rank[i]
__global__ void fillcsr(const int* __restrict__ src_ui, const int* __restrict__ dst_ui,
                        const float* __restrict__ nrm_ui, int nE_ui,
                        const int* __restrict__ src_iu, const int* __restrict__ dst_iu,
                        const float* __restrict__ nrm_iu, int nE_iu,
                        int NU, const int* __restrict__ rowptr,
                        const int* __restrict__ rank, int2* __restrict__ pay) {
  int i = blockIdx.x * blockDim.x + threadIdx.x;
  int stride = gridDim.x * blockDim.x;
  int nTot = nE_ui + nE_iu;
  for (; i < nTot; i += stride) {
    int d, s; float nm;
    if (i < nE_ui) { d = NU + dst_ui[i]; s = src_ui[i]; nm = nrm_ui[i]; }
    else { int k = i - nE_ui; d = dst_iu[k]; s = src_iu[k]; nm = nrm_iu[k]; }
    const int pos = rowptr[d] + rank[i];
    int2 p; p.x = s; p.y = __float_as_int(nm);
    pay[pos] = p;
  }
}

// ---- pullfin v3: S computed inline from payload norms.
// h[r] = A_self[r] + (S-1)*Q[r] - b2 + sum_e norm_e * A_gather[src_e]; lrelu+L2norm.
__global__ __launch_bounds__(256) void pullfin(
    const int* __restrict__ rowptr, const int2* __restrict__ pay,
    const unsigned short* __restrict__ Ac,
    const unsigned short* __restrict__ Au, const unsigned short* __restrict__ Ai,
    const unsigned short* __restrict__ Qc,
    const float* __restrict__ b2,
    float* __restrict__ out, int NU, int ntot) {
  const int lane = threadIdx.x & 63;
  const int h    = lane & 31;
  const int half = lane >> 5;
  float b2v[4];
#pragma unroll
  for (int j = 0; j < 4; ++j) b2v[j] = b2[h * 4 + j];

  int r = (((blockIdx.x * blockDim.x + threadIdx.x) >> 6) << 1) + half;
  const int rstride = ((gridDim.x * blockDim.x) >> 6) << 1;
  for (; r < ntot; r += rstride) {
    const unsigned short* Ag = (r < NU) ? Ai : Au;
    const int beg = rowptr[r], end = rowptr[r + 1];
    float a0 = 0.f, a1 = 0.f, a2 = 0.f, a3 = 0.f, sn = 0.f;
    int e = beg;
    for (; e + 3 < end; e += 4) {
      int2 p0 = pay[e], p1 = pay[e + 1], p2 = pay[e + 2], p3 = pay[e + 3];
      uint2 g0 = *(const uint2*)(Ag + (size_t)p0.x * DDIM + h * 4);
      uint2 g1 = *(const uint2*)(Ag + (size_t)p1.x * DDIM + h * 4);
      uint2 g2 = *(const uint2*)(Ag + (size_t)p2.x * DDIM + h * 4);
      uint2 g3 = *(const uint2*)(Ag + (size_t)p3.x * DDIM + h * 4);
      float n0 = __int_as_float(p0.y), n1 = __int_as_float(p1.y);
      float n2 = __int_as_float(p2.y), n3 = __int_as_float(p3.y);
      sn += (n0 + n1) + (n2 + n3);
      a0 += n0 * bf2f((unsigned short)(g0.x & 0xffffu));
      a1 += n0 * bf2f((unsigned short)(g0.x >> 16));
      a2 += n0 * bf2f((unsigned short)(g0.y & 0xffffu));
      a3 += n0 * bf2f((unsigned short)(g0.y >> 16));
      a0 += n1 * bf2f((unsigned short)(g1.x & 0xffffu));
      a1 += n1 * bf2f((unsigned short)(g1.x >> 16));
      a2 += n1 * bf2f((unsigned short)(g1.y & 0xffffu));
      a3 += n1 * bf2f((unsigned short)(g1.y >> 16));
      a0 += n2 * bf2f((unsigned short)(g2.x & 0xffffu));
      a1 += n2 * bf2f((unsigned short)(g2.x >> 16));
      a2 += n2 * bf2f((unsigned short)(g2.y & 0xffffu));
      a3 += n2 * bf2f((unsigned short)(g2.y >> 16));
      a0 += n3 * bf2f((unsigned short)(g3.x & 0xffffu));
      a1 += n3 * bf2f((unsigned short)(g3.x >> 16));
      a2 += n3 * bf2f((unsigned short)(g3.y & 0xffffu));
      a3 += n3 * bf2f((unsigned short)(g3.y >> 16));
    }
    for (; e < end; ++e) {
      int2 p0 = pay[e];
      uint2 g0 = *(const uint2*)(Ag + (size_t)p0.x * DDIM + h * 4);
      float n0 = __int_as_float(p0.y);
      sn += n0;
      a0 += n0 * bf2f((unsigned short)(g0.x & 0xffffu));
      a1 += n0 * bf2f((unsigned short)(g0.x >> 16));
      a2 += n0 * bf2f((unsigned short)(g0.y & 0xffffu));
      a3 += n0 * bf2f((unsigned short)(g0.y >> 16));
    }

    uint2 av = *(const uint2*)(Ac + (size_t)r * DDIM + h * 4);
    uint2 qv = *(const uint2*)(Qc + (size_t)r * DDIM + h * 4);
    const float s1 = sn - 1.0f;
    float v0 = bf2f((unsigned short)(av.x & 0xffffu)) + s1 * bf2f((unsigned short)(qv.x & 0xffffu)) - b2v[0] + a0;
    float v1 = bf2f((unsigned short)(av.x >> 16))     + s1 * bf2f((unsigned short)(qv.x >> 16))     - b2v[1] + a1;
    float v2 = bf2f((unsigned short)(av.y & 0xffffu)) + s1 * bf2f((unsigned short)(qv.y & 0xffffu)) - b2v[2] + a2;
    float v3 = bf2f((unsigned short)(av.y >> 16))     + s1 * bf2f((unsigned short)(qv.y >> 16))     - b2v[3] + a3;

    v0 = v0 > 0.f ? v0 : 0.2f * v0;
    v1 = v1 > 0.f ? v1 : 0.2f * v1;
    v2 = v2 > 0.f ? v2 : 0.2f * v2;
    v3 = v3 > 0.f ? v3 : 0.2f * v3;
    float sq = v0 * v0 + v1 * v1 + v2 * v2 + v3 * v3;
#pragma unroll
    for (int off = 16; off; off >>= 1) sq += __shfl_xor(sq, off);
    float sc = 1.0f / fmaxf(sqrtf(sq), 1e-12f);
    f32x4 res;
    res.x = v0 * sc; res.y = v1 * sc; res.z = v2 * sc; res.w = v3 * sc;
    __builtin_nontemporal_store(res, (f32x4*)(out + (size_t)r * DDIM + h * 4));
  }
}

extern "C" void kernel_launch(void* const* d_in, const int* in_sizes, int n_in,
                              void* d_out, int out_size, void* d_ws, size_t ws_size,
                              hipStream_t stream) {
  const float* x_user  = (const float*)d_in[0];
  const float* x_item  = (const float*)d_in[1];
  const float* W1      = (const float*)d_in[2];
  const float* b1      = (const float*)d_in[3];
  const float* W2      = (const float*)d_in[4];
  const float* b2      = (const float*)d_in[5];
  const int*   src_ui  = (const int*)d_in[6];
  const int*   dst_ui  = (const int*)d_in[7];
  const float* norm_ui = (const float*)d_in[8];
  const int*   src_iu  = (const int*)d_in[9];
  const int*   dst_iu  = (const int*)d_in[10];
  const float* norm_iu = (const float*)d_in[11];

  const int NUr   = in_sizes[0] / DDIM;   // 100000
  const int NIr   = in_sizes[1] / DDIM;   // 50000
  const int nE_ui = in_sizes[6];          // 300000
  const int nE_iu = in_sizes[9];
  const int nTot  = NUr + NIr;
  const int nETot = nE_ui + nE_iu;

  float* out = (float*)d_out;             // rows: [h_user (NUr); h_item (NIr)]

  char* ws = (char*)d_ws;
  size_t off = 0;
  auto alloc = [&](size_t bytes) { char* p = ws + off; off += (bytes + 15) & ~(size_t)15; return p; };
  unsigned short* wb  = (unsigned short*)alloc(32768 * 2);
  unsigned short* Ac  = (unsigned short*)alloc((size_t)nTot * DDIM * 2);  // [Au; Ai]
  unsigned short* Qc  = (unsigned short*)alloc((size_t)nTot * DDIM * 2);  // [Qu; Qi]
  int*   deg          = (int*)alloc((size_t)nTot * 4);
  int*   exsc         = (int*)alloc((size_t)nTot * 4);
  int*   bsum         = (int*)alloc(256 * 4);
  int*   rowptr       = (int*)alloc(((size_t)nTot + 1) * 4);
  int*   rank         = (int*)alloc((size_t)nETot * 4);
  int2*  pay          = (int2*)alloc((size_t)nETot * 8);

  unsigned short* Au = Ac;
  unsigned short* Ai = Ac + (size_t)NUr * DDIM;
  unsigned short* Qu = Qc;
  unsigned short* Qi = Qc + (size_t)NUr * DDIM;

  (void)hipMemsetAsync(deg, 0, (size_t)nTot * 4, stream);

  const int gU = (NUr + 63) / 64;         // 1563
  const int gI = (NIr + 63) / 64;         // 782
  const int nTiles = gU + gI;             // 2345

  convW<<<128, 256, 0, stream>>>(W1, W2, wb);
  proj<<<1024, 256, 0, stream>>>(x_user, NUr, gU, x_item, NIr, nTiles,
                                 wb, b1, b2, Au, Qu, Ai, Qi);
  hist<<<4096, 256, 0, stream>>>(dst_ui, nE_ui, dst_iu, nE_iu, NUr, deg, rank);

  const int nb = (nTot + 1023) / 1024;    // 147
  scan1<<<nb, 1024, 0, stream>>>(deg, nTot, exsc, bsum);
  scan2<<<1, 256, 0, stream>>>(bsum, nb);
  scan3<<<(nTot + 256) / 256, 256, 0, stream>>>(exsc, bsum, nTot, nETot, rowptr);
  fillcsr<<<2048, 256, 0, stream>>>(src_ui, dst_ui, norm_ui, nE_ui,
                                    src_iu, dst_iu, norm_iu, nE_iu, NUr, rowptr, rank, pay);
  pullfin<<<18752, 256, 0, stream>>>(rowptr, pay, Ac, Au, Ai, Qc, b2, out, NUr, nTot);
}